// Round 12
// baseline (6135.926 us; speedup 1.0000x reference)
//
#include <hip/hip_runtime.h>
#include <cstdint>
#include <cstddef>
#include <cfloat>

// Persistent Seq2Seq LSTM v10 (B=32,S=T=64,E=256,H=512,V=32000), fp32.
// R12 = R10 exactly (two-level barrier, fresh-buffer cached broadcast, fcW in
// VGPRs) + register-carry of per-thread h slices across decoder phases:
//   - hv0(t+1) == xv1(t) slice (same generation) -> carried, phase-1 stage cut
//   - hv1(t+1) == fc-phase staged h1new slice    -> carried, phase-2 stage cut
//   - masked h_old[bb][j] owned by one thread     -> register, no LDS dep
// Decoder: 4 -> 2 broadcast stages/step. R11's flat barrier + prefetch REVERTED.

#define NWG   256
#define NTHR  512
#define BSZ   32
#define SLEN  64
#define TLEN  64
#define EDIM  256
#define HDIM  512
#define VOUT  32000
#define FCWGS 250
#define FCR   128
#define FSTR  16

#define XS0 20
#define HSL 36
#define RS0 (16 * XS0 + 16 * HSL)
#define RS1 (16 * HSL + 16 * HSL)
#define HB  576
#define HGEN 16384          // floats per h generation (64KB)
#define NHG_FRESH 258
#define NHG_FB    8
#define NCG_FRESH 64
#define NCG_FB    2

struct SMem {
    float w0[8 * RS0];
    float w1[8 * RS1];
    float hst[32 * HB];
    float zsh0[8 * 32];
    float zsh1[8 * 32];
    float cmv[32 * 32];
    int   cmi[32 * 32];
    float bsum0[8], bsum1[8];
    float fcb_s[FCR];
    int   tok[BSZ];
    int   llen[BSZ];
};

// ------------------------------------------------- relaxed agent atomics ----
__device__ __forceinline__ void astore(float* p, float v) {
    __hip_atomic_store(p, v, __ATOMIC_RELAXED, __HIP_MEMORY_SCOPE_AGENT);
}
__device__ __forceinline__ void astorei(int* p, int v) {
    __hip_atomic_store(p, v, __ATOMIC_RELAXED, __HIP_MEMORY_SCOPE_AGENT);
}
__device__ __forceinline__ float2 aload2(const float* p) {
    unsigned long long u = __hip_atomic_load((const unsigned long long*)p,
                              __ATOMIC_RELAXED, __HIP_MEMORY_SCOPE_AGENT);
    union { unsigned long long u; float2 f; } c; c.u = u; return c.f;
}

// -------------------------------------------------- buffer generation map ---
__device__ __forceinline__ int fbmap(int g) {
    if (g < 65)  return (g & 1);
    if (g < 130) return 2 + ((g - 65) & 1);
    if (g < 194) return 4 + ((g - 130) & 1);
    return 6 + ((g - 194) & 1);
}
__device__ __forceinline__ float* genp(float* hb, int g, int fresh) {
    return hb + (size_t)(fresh ? g : fbmap(g)) * HGEN;
}

// ---------------------------------------------------------- grid barrier ----
// Two-level, fence-free (identical to R6/R7/R10 — proven).
__device__ __forceinline__ void gridbar(unsigned* flags, unsigned* sense,
                                        unsigned& epoch)
{
    asm volatile("s_waitcnt vmcnt(0)" ::: "memory");
    __syncthreads();
    epoch++;
    const int tid = threadIdx.x;
    if (tid == 0)
        __hip_atomic_store(&flags[(size_t)blockIdx.x * FSTR], epoch,
                           __ATOMIC_RELAXED, __HIP_MEMORY_SCOPE_AGENT);
    if (blockIdx.x == 0) {
        if (tid < 64) {
#pragma unroll
            for (int k = 0; k < 4; k++) {
                const size_t idx = (size_t)(tid * 4 + k) * FSTR;
                while (__hip_atomic_load(&flags[idx], __ATOMIC_RELAXED,
                                         __HIP_MEMORY_SCOPE_AGENT) < epoch)
                    __builtin_amdgcn_s_sleep(2);
            }
        }
        __syncthreads();
        if (tid == 0)
            __hip_atomic_store(sense, epoch, __ATOMIC_RELAXED,
                               __HIP_MEMORY_SCOPE_AGENT);
    }
    if (tid == 0) {
        while (__hip_atomic_load(sense, __ATOMIC_RELAXED,
                                 __HIP_MEMORY_SCOPE_AGENT) < epoch)
            __builtin_amdgcn_s_sleep(4);
    }
    __syncthreads();
}

// ------------------------------------------------- h staging (dual path) ----
__device__ __forceinline__ void stage_h(float* hst, const float* __restrict__ hg,
                                        int cached)
{
    const int t = threadIdx.x;
    if (cached) {
#pragma unroll
        for (int i = 0; i < 8; i++) {
            int f = i * 2048 + t * 4;
            float4 v = *(const float4*)(hg + f);
            int b = f >> 9, j = f & 511;
            *(float4*)(&hst[b * HB + (j >> 5) * 36 + (j & 31)]) = v;
        }
    } else {
#pragma unroll
        for (int i = 0; i < 16; i++) {
            int f = i * 1024 + t * 2;
            float2 v = aload2(hg + f);
            int b = f >> 9, j = f & 511;
            *(float2*)(&hst[b * HB + (j >> 5) * 36 + (j & 31)]) = v;
        }
    }
}
__device__ __forceinline__ void read_slice32(const float* hst, int b, int kq,
                                             float* dst)
{
#pragma unroll
    for (int i = 0; i < 8; i++) {
        float4 v = *(const float4*)(hst + b * HB + kq * 36 + i * 4);
        dst[i * 4 + 0] = v.x; dst[i * 4 + 1] = v.y;
        dst[i * 4 + 2] = v.z; dst[i * 4 + 3] = v.w;
    }
}

// ------------------------------------------------------- weight staging -----
template<int KIN>
__device__ __forceinline__ void stage_w(float* dst,
        const float* __restrict__ Wih, const float* __restrict__ Whh,
        const float* __restrict__ bih, const float* __restrict__ bhh,
        float* bsum, int j0)
{
    constexpr int XC = KIN / 16;
    constexpr int XS = (KIN == 256) ? XS0 : HSL;
    constexpr int RS = (KIN == 256) ? RS0 : RS1;
    const int tid = threadIdx.x;
    constexpr int nf4x = KIN / 4;
    for (int tt = tid; tt < 8 * nf4x; tt += NTHR) {
        int r = tt / nf4x, k = (tt % nf4x) * 4;
        int row = (r >> 1) * HDIM + j0 + (r & 1);
        float4 v = *(const float4*)(Wih + (size_t)row * KIN + k);
        *(float4*)(dst + r * RS + (k / XC) * XS + (k % XC)) = v;
    }
    for (int tt = tid; tt < 8 * 128; tt += NTHR) {
        int r = tt >> 7, k = (tt & 127) * 4;
        int row = (r >> 1) * HDIM + j0 + (r & 1);
        float4 v = *(const float4*)(Whh + (size_t)row * HDIM + k);
        *(float4*)(dst + r * RS + 16 * XS + (k >> 5) * HSL + (k & 31)) = v;
    }
    if (tid < 8) {
        int row = (tid >> 1) * HDIM + j0 + (tid & 1);
        bsum[tid] = bih[row] + bhh[row];
    }
}

// ------------------------------------------------------------- LSTM cell ----
// hold: per-thread register holding h_old[bb][j] (tid<64 lanes only).
template<int KIN>
__device__ __forceinline__ void cell_compute(SMem& sm, const float* __restrict__ w,
        const float* bsum, const float* xv, const float* hv,
        float* __restrict__ hout, float& creg, float& hold,
        bool domask, int s, int j0, float* zsh)
{
    constexpr int XC = KIN / 16;
    constexpr int XS = (KIN == 256) ? XS0 : HSL;
    constexpr int RS = (KIN == 256) ? RS0 : RS1;
    const int tid = threadIdx.x;
    const int wave = tid >> 6, lane = tid & 63, kq = lane & 15, bl = lane >> 4;
    const int b = wave * 4 + bl;

#pragma unroll
    for (int r = 0; r < 8; r++) {
        float acc = 0.f;
        const float* wx = w + r * RS + kq * XS;
#pragma unroll
        for (int i = 0; i < XC / 4; i++) {
            float4 t4 = *(const float4*)(wx + i * 4);
            acc += t4.x * xv[i*4] + t4.y * xv[i*4+1] + t4.z * xv[i*4+2] + t4.w * xv[i*4+3];
        }
        const float* wh = w + r * RS + 16 * XS + kq * HSL;
#pragma unroll
        for (int i = 0; i < 8; i++) {
            float4 t4 = *(const float4*)(wh + i * 4);
            acc += t4.x * hv[i*4] + t4.y * hv[i*4+1] + t4.z * hv[i*4+2] + t4.w * hv[i*4+3];
        }
        acc += __shfl_xor(acc, 1);
        acc += __shfl_xor(acc, 2);
        acc += __shfl_xor(acc, 4);
        acc += __shfl_xor(acc, 8);
        if (kq == 0) zsh[r * 32 + b] = acc + bsum[r];
    }
    __syncthreads();
    if (tid < 64) {
        int jl = tid >> 5, bb = tid & 31;
        float zi = zsh[(0 + jl) * 32 + bb];
        float zf = zsh[(2 + jl) * 32 + bb];
        float zg = zsh[(4 + jl) * 32 + bb];
        float zo = zsh[(6 + jl) * 32 + bb];
        float iv = 1.f / (1.f + expf(-zi));
        float fv = 1.f / (1.f + expf(-zf));
        float gv = tanhf(zg);
        float ov = 1.f / (1.f + expf(-zo));
        float cold = creg;
        float c2 = fv * cold + iv * gv;
        float h2 = ov * tanhf(c2);
        if (domask) {
            bool m = s < sm.llen[bb];
            if (!m) { h2 = hold; c2 = cold; }
        }
        hold = h2;
        astore(hout + (size_t)bb * HDIM + (j0 + jl), h2);
        creg = c2;
    }
}

// ---------------------------------- fc (weights in VGPRs; hst pre-staged) ---
__device__ __forceinline__ void fc_run(SMem& sm, const float4 (&wfc)[4][8],
        float* __restrict__ out, int t, int g,
        float* __restrict__ cand_val, int* __restrict__ cand_idx)
{
    const int tid = threadIdx.x;
    const int kh = tid & 15, rg = tid >> 4;
    const int v0 = g * FCR;

    float bias[4];
#pragma unroll
    for (int r = 0; r < 4; r++) bias[r] = sm.fcb_s[rg * 4 + r];

    for (int b = 0; b < 32; b++) {
        float hv[32];
        read_slice32(sm.hst, b, kh, hv);
        float a0 = 0.f, a1 = 0.f, a2 = 0.f, a3 = 0.f;
#pragma unroll
        for (int i = 0; i < 8; i++) {
            float4 w0 = wfc[0][i], w1 = wfc[1][i], w2 = wfc[2][i], w3 = wfc[3][i];
            float h0 = hv[i*4], h1 = hv[i*4+1], h2 = hv[i*4+2], h3 = hv[i*4+3];
            a0 += w0.x * h0 + w0.y * h1 + w0.z * h2 + w0.w * h3;
            a1 += w1.x * h0 + w1.y * h1 + w1.z * h2 + w1.w * h3;
            a2 += w2.x * h0 + w2.y * h1 + w2.z * h2 + w2.w * h3;
            a3 += w3.x * h0 + w3.y * h1 + w3.z * h2 + w3.w * h3;
        }
#pragma unroll
        for (int m = 1; m < 16; m <<= 1) {
            a0 += __shfl_xor(a0, m);
            a1 += __shfl_xor(a1, m);
            a2 += __shfl_xor(a2, m);
            a3 += __shfl_xor(a3, m);
        }
        if (kh == 0) {
            float z0 = a0 + bias[0], z1 = a1 + bias[1];
            float z2 = a2 + bias[2], z3 = a3 + bias[3];
            *(float4*)(out + ((size_t)b * TLEN + t) * VOUT + v0 + rg * 4)
                = make_float4(z0, z1, z2, z3);
            float lm = z0; int li = 0;                 // ascending r: strict >
            if (z1 > lm) { lm = z1; li = 1; }
            if (z2 > lm) { lm = z2; li = 2; }
            if (z3 > lm) { lm = z3; li = 3; }
            sm.cmv[rg * 32 + b] = lm;
            sm.cmi[rg * 32 + b] = v0 + rg * 4 + li;
        }
    }
    __syncthreads();
    if (tid < 32) {
        float bv = sm.cmv[tid]; int bi = sm.cmi[tid];
#pragma unroll
        for (int r2 = 1; r2 < 32; r2++) {
            float v = sm.cmv[r2 * 32 + tid]; int ix = sm.cmi[r2 * 32 + tid];
            if (v > bv || (v == bv && ix < bi)) { bv = v; bi = ix; }
        }
        astore(&cand_val[(size_t)tid * NWG + g], bv);
        astorei(&cand_idx[(size_t)tid * NWG + g], bi);
    }
}

// --------------------------------------------------------- main persistent --
__global__ __launch_bounds__(NTHR, 2)
void seq2seq_persist(
    const int* __restrict__ inputs, const int* __restrict__ lens,
    const float* __restrict__ enc_emb, const float* __restrict__ dec_emb,
    const float* __restrict__ eW0ih, const float* __restrict__ eW0hh,
    const float* __restrict__ eB0ih, const float* __restrict__ eB0hh,
    const float* __restrict__ eW1ih, const float* __restrict__ eW1hh,
    const float* __restrict__ eB1ih, const float* __restrict__ eB1hh,
    const float* __restrict__ dW0ih, const float* __restrict__ dW0hh,
    const float* __restrict__ dB0ih, const float* __restrict__ dB0hh,
    const float* __restrict__ dW1ih, const float* __restrict__ dW1hh,
    const float* __restrict__ dB1ih, const float* __restrict__ dB1hh,
    const float* __restrict__ fcW, const float* __restrict__ fcb,
    float* __restrict__ out,
    float* hb, float* cb, unsigned* flags, unsigned* sense, int fresh)
{
    __shared__ SMem sm;
    const int g = blockIdx.x;
    const int tid = threadIdx.x;
    const int j0 = g * 2;
    unsigned epoch = 0;

    // entry: invalidate cache lines retained from a previous graph replay
    __builtin_amdgcn_fence(__ATOMIC_ACQUIRE, "agent");

    const int wave = tid >> 6, lane = tid & 63, kq16 = lane & 15, bl = lane >> 4;
    const int b = wave * 4 + bl;

    if (tid < 64) {
        astore(&genp(hb, 0, fresh)[g * 64 + tid], 0.f);    // h0e[0]
        astore(&genp(hb, 65, fresh)[g * 64 + tid], 0.f);   // h1e[0]
    }
    stage_w<EDIM>(sm.w0, eW0ih, eW0hh, eB0ih, eB0hh, sm.bsum0, j0);
    stage_w<HDIM>(sm.w1, eW1ih, eW1hh, eB1ih, eB1hh, sm.bsum1, j0);
    if (tid < BSZ) sm.llen[tid] = lens[tid];
    float c0r = 0.f, c1r = 0.f;
    float hold0 = 0.f, hold1 = 0.f;    // per-thread h_old[bb][j] registers
    float hv0c[32], hv1c[32];          // carried per-thread h slices
    gridbar(flags, sense, epoch);

    // ---- encoder: pipelined (cell0(s) || cell1(s-1)), 1 barrier/phase ----
    // gens: h0e[k]=k (0..64), h1e[k]=65+k (65..129)
    for (int s = 0; s <= SLEN; ++s) {
        stage_h(sm.hst, genp(hb, s, fresh), fresh);
        __syncthreads();
        float xv0[16], hv0[32], xv1[32];
        if (s < SLEN) {
            int tokv = inputs[b * SLEN + s];
            const float* x0 = enc_emb + (size_t)tokv * EDIM;
#pragma unroll
            for (int i = 0; i < 4; i++) {
                float4 v = *(const float4*)(x0 + kq16 * 16 + i * 4);
                xv0[i*4] = v.x; xv0[i*4+1] = v.y; xv0[i*4+2] = v.z; xv0[i*4+3] = v.w;
            }
            read_slice32(sm.hst, b, kq16, hv0);
        }
        if (s >= 1) read_slice32(sm.hst, b, kq16, xv1);
        if (s < SLEN)
            cell_compute<EDIM>(sm, sm.w0, sm.bsum0, xv0, hv0,
                               genp(hb, s + 1, fresh), c0r, hold0, true, s, j0, sm.zsh0);
        __syncthreads();
        if (s >= 1) {
            stage_h(sm.hst, genp(hb, 65 + s - 1, fresh), fresh);
            __syncthreads();
            float hv1[32];
            read_slice32(sm.hst, b, kq16, hv1);
            cell_compute<HDIM>(sm, sm.w1, sm.bsum1, xv1, hv1,
                               genp(hb, 65 + s, fresh), c1r, hold1, true, s - 1, j0, sm.zsh1);
        }
        if (s == SLEN) {
#pragma unroll
            for (int i = 0; i < 32; i++) hv0c[i] = xv1[i];  // gen 64 slice = dec h0old
        }
        gridbar(flags, sense, epoch);
    }
    // encoder finals: h0e[64] = gen 64 (carried in hv0c), h1e[64] = gen 129

    // ---- decoder setup: stage dec weights + load fcW into registers ----
    stage_w<EDIM>(sm.w0, dW0ih, dW0hh, dB0ih, dB0hh, sm.bsum0, j0);
    stage_w<HDIM>(sm.w1, dW1ih, dW1hh, dB1ih, dB1hh, sm.bsum1, j0);
    float4 wfc[4][8];
    {
        const int kh = tid & 15, rg = tid >> 4;
        if (g < FCWGS) {
            const float* wp = fcW + ((size_t)g * FCR + rg * 4) * HDIM + kh * 32;
#pragma unroll
            for (int r = 0; r < 4; r++)
#pragma unroll
                for (int i = 0; i < 8; i++)
                    wfc[r][i] = *(const float4*)(wp + (size_t)r * HDIM + i * 4);
            for (int i = tid; i < FCR; i += NTHR) sm.fcb_s[i] = fcb[g * FCR + i];
        }
    }
    c0r = 0.f; c1r = 0.f;
    __syncthreads();

    // gens: h0d out = 130+t, h1d out = 194+t; h1d[0] in = 129
    for (int t = 0; t < TLEN; ++t) {
        const int g0o = 130 + t;
        const int g1o = 194 + t;
        // ---- phase 1: argmax + cell0 (h0old slice carried in hv0c) ----
        if (t == 0) {
            if (tid < BSZ) sm.tok[tid] = 1;
        } else {
            const float* cvp = cb + (size_t)(fresh ? (t - 1) : ((t - 1) & 1)) * HGEN;
            const float* cip = cvp + 8192;
            if (fresh) {
#pragma unroll
                for (int i = 0; i < 4; i++) {
                    int f = i * 2048 + tid * 4;
                    *(float4*)(sm.hst + f) = *(const float4*)(cvp + f);
                    *(float4*)(sm.hst + 8192 + f) = *(const float4*)(cip + f);
                }
            } else {
#pragma unroll
                for (int i = 0; i < 8; i++) {
                    int f = i * 1024 + tid * 2;
                    *(float2*)(sm.hst + f) = aload2(cvp + f);
                    *(float2*)(sm.hst + 8192 + f) = aload2(cip + f);
                }
            }
            __syncthreads();
            if (tid < 256) {
                int bq = tid >> 3, q = tid & 7;
                float bv = -FLT_MAX; int bi = 0x7fffffff;
                for (int gg = q; gg < FCWGS; gg += 8) {
                    float v = sm.hst[bq * 256 + gg];
                    int ix = ((const int*)sm.hst)[8192 + bq * 256 + gg];
                    if (v > bv || (v == bv && ix < bi)) { bv = v; bi = ix; }
                }
#pragma unroll
                for (int m = 1; m < 8; m <<= 1) {
                    float ov = __shfl_xor(bv, m); int oi = __shfl_xor(bi, m);
                    if (ov > bv || (ov == bv && oi < bi)) { bv = ov; bi = oi; }
                }
                if (q == 0) sm.tok[bq] = bi;
            }
        }
        __syncthreads();
        {
            const float* x0 = dec_emb + (size_t)sm.tok[b] * EDIM;
            float xv0[16];
#pragma unroll
            for (int i = 0; i < 4; i++) {
                float4 v = *(const float4*)(x0 + kq16 * 16 + i * 4);
                xv0[i*4] = v.x; xv0[i*4+1] = v.y; xv0[i*4+2] = v.z; xv0[i*4+3] = v.w;
            }
            cell_compute<EDIM>(sm, sm.w0, sm.bsum0, xv0, hv0c,
                               genp(hb, g0o, fresh), c0r, hold0, false, 0, j0, sm.zsh0);
        }
        gridbar(flags, sense, epoch);
        // ---- phase 2: cell1 (x = h0new staged; h1old slice carried) ----
        stage_h(sm.hst, genp(hb, g0o, fresh), fresh);
        __syncthreads();
        float xv1[32];
        read_slice32(sm.hst, b, kq16, xv1);
#pragma unroll
        for (int i = 0; i < 32; i++) hv0c[i] = xv1[i];   // carry for next cell0
        if (t == 0) {
            __syncthreads();
            stage_h(sm.hst, genp(hb, 129, fresh), fresh);   // enc final h1
            __syncthreads();
            read_slice32(sm.hst, b, kq16, hv1c);
        }
        __syncthreads();
        cell_compute<HDIM>(sm, sm.w1, sm.bsum1, xv1, hv1c,
                           genp(hb, g1o, fresh), c1r, hold1, false, 0, j0, sm.zsh1);
        gridbar(flags, sense, epoch);
        // ---- phase 3: stage h1new (all WGs) -> carry + fc ----
        stage_h(sm.hst, genp(hb, g1o, fresh), fresh);
        __syncthreads();
        read_slice32(sm.hst, b, kq16, hv1c);             // carry for next cell1
        if (g < FCWGS) {
            float* cvt = cb + (size_t)(fresh ? t : (t & 1)) * HGEN;
            fc_run(sm, wfc, out, t, g, cvt, (int*)(cvt + 8192));
        }
        if (t < TLEN - 1)
            gridbar(flags, sense, epoch);
    }
}

// ------------------------------------------------------------------- init ---
__global__ void initk(unsigned* flags)
{
    int i = blockIdx.x * 256 + threadIdx.x;
    if (i < NWG * FSTR + 16) flags[i] = 0u;
}

// ----------------------------------------------------------------- driver ---
extern "C" void kernel_launch(void* const* d_in, const int* in_sizes, int n_in,
                              void* d_out, int out_size, void* d_ws, size_t ws_size,
                              hipStream_t stream)
{
    const int*   inputs  = (const int*)d_in[0];
    const int*   lens    = (const int*)d_in[3];
    const float* enc_emb = (const float*)d_in[4];
    const float* dec_emb = (const float*)d_in[5];
    const float* W[16];
    for (int i = 0; i < 16; i++) W[i] = (const float*)d_in[6 + i];
    const float* fcW = (const float*)d_in[22];
    const float* fcb = (const float*)d_in[23];
    float* out = (float*)d_out;

    float* ws = (float*)d_ws;
    unsigned* flags = (unsigned*)ws;                   // 256*16 + sense line
    float* hb = ws + 8192;                             // h generations
    size_t needB = (size_t)(8192 + (NHG_FRESH + NCG_FRESH) * HGEN) * 4;
    int fresh = (ws_size >= needB) ? 1 : 0;
    float* cb = hb + (size_t)(fresh ? NHG_FRESH : NHG_FB) * HGEN;

    initk<<<17, 256, 0, stream>>>(flags);
    seq2seq_persist<<<NWG, NTHR, 0, stream>>>(
        inputs, lens, enc_emb, dec_emb,
        W[0], W[1], W[2], W[3], W[4], W[5], W[6], W[7],
        W[8], W[9], W[10], W[11], W[12], W[13], W[14], W[15],
        fcW, fcb, out,
        hb, cb, flags, flags + NWG * FSTR, fresh);
}

// Round 13
// 6131.875 us; speedup vs baseline: 1.0007x; 1.0007x over previous
//
#include <hip/hip_runtime.h>
#include <cstdint>
#include <cstddef>
#include <cfloat>

// Persistent Seq2Seq LSTM v11 (B=32,S=T=64,E=256,H=512,V=32000), fp32.
// R13 = R12 with ONE change: __launch_bounds__(512, 1) instead of (512, 2).
// R12's regression was VGPR-cap-induced scratch spill (FETCH +209MB, WRITE
// +107MB, VGPR pinned 128): the (512,2) bound promised 2 blocks/CU which LDS
// (150KB) can never satisfy, so the carried h slices spilled. (512,1) frees
// the allocator to ~256 VGPRs at the SAME real occupancy (1 WG/CU).
// Structure: R10 base (two-level fence-free barrier, fresh-buffer cached
// broadcast, fcW in VGPRs) + register-carry of h slices (2 stages/dec step).

#define NWG   256
#define NTHR  512
#define BSZ   32
#define SLEN  64
#define TLEN  64
#define EDIM  256
#define HDIM  512
#define VOUT  32000
#define FCWGS 250
#define FCR   128
#define FSTR  16

#define XS0 20
#define HSL 36
#define RS0 (16 * XS0 + 16 * HSL)
#define RS1 (16 * HSL + 16 * HSL)
#define HB  576
#define HGEN 16384          // floats per h generation (64KB)
#define NHG_FRESH 258
#define NHG_FB    8
#define NCG_FRESH 64
#define NCG_FB    2

struct SMem {
    float w0[8 * RS0];
    float w1[8 * RS1];
    float hst[32 * HB];
    float zsh0[8 * 32];
    float zsh1[8 * 32];
    float cmv[32 * 32];
    int   cmi[32 * 32];
    float bsum0[8], bsum1[8];
    float fcb_s[FCR];
    int   tok[BSZ];
    int   llen[BSZ];
};

// ------------------------------------------------- relaxed agent atomics ----
__device__ __forceinline__ void astore(float* p, float v) {
    __hip_atomic_store(p, v, __ATOMIC_RELAXED, __HIP_MEMORY_SCOPE_AGENT);
}
__device__ __forceinline__ void astorei(int* p, int v) {
    __hip_atomic_store(p, v, __ATOMIC_RELAXED, __HIP_MEMORY_SCOPE_AGENT);
}
__device__ __forceinline__ float2 aload2(const float* p) {
    unsigned long long u = __hip_atomic_load((const unsigned long long*)p,
                              __ATOMIC_RELAXED, __HIP_MEMORY_SCOPE_AGENT);
    union { unsigned long long u; float2 f; } c; c.u = u; return c.f;
}

// -------------------------------------------------- buffer generation map ---
__device__ __forceinline__ int fbmap(int g) {
    if (g < 65)  return (g & 1);
    if (g < 130) return 2 + ((g - 65) & 1);
    if (g < 194) return 4 + ((g - 130) & 1);
    return 6 + ((g - 194) & 1);
}
__device__ __forceinline__ float* genp(float* hb, int g, int fresh) {
    return hb + (size_t)(fresh ? g : fbmap(g)) * HGEN;
}

// ---------------------------------------------------------- grid barrier ----
// Two-level, fence-free (identical to R6/R7/R10 — proven).
__device__ __forceinline__ void gridbar(unsigned* flags, unsigned* sense,
                                        unsigned& epoch)
{
    asm volatile("s_waitcnt vmcnt(0)" ::: "memory");
    __syncthreads();
    epoch++;
    const int tid = threadIdx.x;
    if (tid == 0)
        __hip_atomic_store(&flags[(size_t)blockIdx.x * FSTR], epoch,
                           __ATOMIC_RELAXED, __HIP_MEMORY_SCOPE_AGENT);
    if (blockIdx.x == 0) {
        if (tid < 64) {
#pragma unroll
            for (int k = 0; k < 4; k++) {
                const size_t idx = (size_t)(tid * 4 + k) * FSTR;
                while (__hip_atomic_load(&flags[idx], __ATOMIC_RELAXED,
                                         __HIP_MEMORY_SCOPE_AGENT) < epoch)
                    __builtin_amdgcn_s_sleep(2);
            }
        }
        __syncthreads();
        if (tid == 0)
            __hip_atomic_store(sense, epoch, __ATOMIC_RELAXED,
                               __HIP_MEMORY_SCOPE_AGENT);
    }
    if (tid == 0) {
        while (__hip_atomic_load(sense, __ATOMIC_RELAXED,
                                 __HIP_MEMORY_SCOPE_AGENT) < epoch)
            __builtin_amdgcn_s_sleep(4);
    }
    __syncthreads();
}

// ------------------------------------------------- h staging (dual path) ----
__device__ __forceinline__ void stage_h(float* hst, const float* __restrict__ hg,
                                        int cached)
{
    const int t = threadIdx.x;
    if (cached) {
#pragma unroll
        for (int i = 0; i < 8; i++) {
            int f = i * 2048 + t * 4;
            float4 v = *(const float4*)(hg + f);
            int b = f >> 9, j = f & 511;
            *(float4*)(&hst[b * HB + (j >> 5) * 36 + (j & 31)]) = v;
        }
    } else {
#pragma unroll
        for (int i = 0; i < 16; i++) {
            int f = i * 1024 + t * 2;
            float2 v = aload2(hg + f);
            int b = f >> 9, j = f & 511;
            *(float2*)(&hst[b * HB + (j >> 5) * 36 + (j & 31)]) = v;
        }
    }
}
__device__ __forceinline__ void read_slice32(const float* hst, int b, int kq,
                                             float* dst)
{
#pragma unroll
    for (int i = 0; i < 8; i++) {
        float4 v = *(const float4*)(hst + b * HB + kq * 36 + i * 4);
        dst[i * 4 + 0] = v.x; dst[i * 4 + 1] = v.y;
        dst[i * 4 + 2] = v.z; dst[i * 4 + 3] = v.w;
    }
}

// ------------------------------------------------------- weight staging -----
template<int KIN>
__device__ __forceinline__ void stage_w(float* dst,
        const float* __restrict__ Wih, const float* __restrict__ Whh,
        const float* __restrict__ bih, const float* __restrict__ bhh,
        float* bsum, int j0)
{
    constexpr int XC = KIN / 16;
    constexpr int XS = (KIN == 256) ? XS0 : HSL;
    constexpr int RS = (KIN == 256) ? RS0 : RS1;
    const int tid = threadIdx.x;
    constexpr int nf4x = KIN / 4;
    for (int tt = tid; tt < 8 * nf4x; tt += NTHR) {
        int r = tt / nf4x, k = (tt % nf4x) * 4;
        int row = (r >> 1) * HDIM + j0 + (r & 1);
        float4 v = *(const float4*)(Wih + (size_t)row * KIN + k);
        *(float4*)(dst + r * RS + (k / XC) * XS + (k % XC)) = v;
    }
    for (int tt = tid; tt < 8 * 128; tt += NTHR) {
        int r = tt >> 7, k = (tt & 127) * 4;
        int row = (r >> 1) * HDIM + j0 + (r & 1);
        float4 v = *(const float4*)(Whh + (size_t)row * HDIM + k);
        *(float4*)(dst + r * RS + 16 * XS + (k >> 5) * HSL + (k & 31)) = v;
    }
    if (tid < 8) {
        int row = (tid >> 1) * HDIM + j0 + (tid & 1);
        bsum[tid] = bih[row] + bhh[row];
    }
}

// ------------------------------------------------------------- LSTM cell ----
// hold: per-thread register holding h_old[bb][j] (tid<64 lanes only).
template<int KIN>
__device__ __forceinline__ void cell_compute(SMem& sm, const float* __restrict__ w,
        const float* bsum, const float* xv, const float* hv,
        float* __restrict__ hout, float& creg, float& hold,
        bool domask, int s, int j0, float* zsh)
{
    constexpr int XC = KIN / 16;
    constexpr int XS = (KIN == 256) ? XS0 : HSL;
    constexpr int RS = (KIN == 256) ? RS0 : RS1;
    const int tid = threadIdx.x;
    const int wave = tid >> 6, lane = tid & 63, kq = lane & 15, bl = lane >> 4;
    const int b = wave * 4 + bl;

#pragma unroll
    for (int r = 0; r < 8; r++) {
        float acc = 0.f;
        const float* wx = w + r * RS + kq * XS;
#pragma unroll
        for (int i = 0; i < XC / 4; i++) {
            float4 t4 = *(const float4*)(wx + i * 4);
            acc += t4.x * xv[i*4] + t4.y * xv[i*4+1] + t4.z * xv[i*4+2] + t4.w * xv[i*4+3];
        }
        const float* wh = w + r * RS + 16 * XS + kq * HSL;
#pragma unroll
        for (int i = 0; i < 8; i++) {
            float4 t4 = *(const float4*)(wh + i * 4);
            acc += t4.x * hv[i*4] + t4.y * hv[i*4+1] + t4.z * hv[i*4+2] + t4.w * hv[i*4+3];
        }
        acc += __shfl_xor(acc, 1);
        acc += __shfl_xor(acc, 2);
        acc += __shfl_xor(acc, 4);
        acc += __shfl_xor(acc, 8);
        if (kq == 0) zsh[r * 32 + b] = acc + bsum[r];
    }
    __syncthreads();
    if (tid < 64) {
        int jl = tid >> 5, bb = tid & 31;
        float zi = zsh[(0 + jl) * 32 + bb];
        float zf = zsh[(2 + jl) * 32 + bb];
        float zg = zsh[(4 + jl) * 32 + bb];
        float zo = zsh[(6 + jl) * 32 + bb];
        float iv = 1.f / (1.f + expf(-zi));
        float fv = 1.f / (1.f + expf(-zf));
        float gv = tanhf(zg);
        float ov = 1.f / (1.f + expf(-zo));
        float cold = creg;
        float c2 = fv * cold + iv * gv;
        float h2 = ov * tanhf(c2);
        if (domask) {
            bool m = s < sm.llen[bb];
            if (!m) { h2 = hold; c2 = cold; }
        }
        hold = h2;
        astore(hout + (size_t)bb * HDIM + (j0 + jl), h2);
        creg = c2;
    }
}

// ---------------------------------- fc (weights in VGPRs; hst pre-staged) ---
__device__ __forceinline__ void fc_run(SMem& sm, const float4 (&wfc)[4][8],
        float* __restrict__ out, int t, int g,
        float* __restrict__ cand_val, int* __restrict__ cand_idx)
{
    const int tid = threadIdx.x;
    const int kh = tid & 15, rg = tid >> 4;
    const int v0 = g * FCR;

    float bias[4];
#pragma unroll
    for (int r = 0; r < 4; r++) bias[r] = sm.fcb_s[rg * 4 + r];

    for (int b = 0; b < 32; b++) {
        float hv[32];
        read_slice32(sm.hst, b, kh, hv);
        float a0 = 0.f, a1 = 0.f, a2 = 0.f, a3 = 0.f;
#pragma unroll
        for (int i = 0; i < 8; i++) {
            float4 w0 = wfc[0][i], w1 = wfc[1][i], w2 = wfc[2][i], w3 = wfc[3][i];
            float h0 = hv[i*4], h1 = hv[i*4+1], h2 = hv[i*4+2], h3 = hv[i*4+3];
            a0 += w0.x * h0 + w0.y * h1 + w0.z * h2 + w0.w * h3;
            a1 += w1.x * h0 + w1.y * h1 + w1.z * h2 + w1.w * h3;
            a2 += w2.x * h0 + w2.y * h1 + w2.z * h2 + w2.w * h3;
            a3 += w3.x * h0 + w3.y * h1 + w3.z * h2 + w3.w * h3;
        }
#pragma unroll
        for (int m = 1; m < 16; m <<= 1) {
            a0 += __shfl_xor(a0, m);
            a1 += __shfl_xor(a1, m);
            a2 += __shfl_xor(a2, m);
            a3 += __shfl_xor(a3, m);
        }
        if (kh == 0) {
            float z0 = a0 + bias[0], z1 = a1 + bias[1];
            float z2 = a2 + bias[2], z3 = a3 + bias[3];
            *(float4*)(out + ((size_t)b * TLEN + t) * VOUT + v0 + rg * 4)
                = make_float4(z0, z1, z2, z3);
            float lm = z0; int li = 0;                 // ascending r: strict >
            if (z1 > lm) { lm = z1; li = 1; }
            if (z2 > lm) { lm = z2; li = 2; }
            if (z3 > lm) { lm = z3; li = 3; }
            sm.cmv[rg * 32 + b] = lm;
            sm.cmi[rg * 32 + b] = v0 + rg * 4 + li;
        }
    }
    __syncthreads();
    if (tid < 32) {
        float bv = sm.cmv[tid]; int bi = sm.cmi[tid];
#pragma unroll
        for (int r2 = 1; r2 < 32; r2++) {
            float v = sm.cmv[r2 * 32 + tid]; int ix = sm.cmi[r2 * 32 + tid];
            if (v > bv || (v == bv && ix < bi)) { bv = v; bi = ix; }
        }
        astore(&cand_val[(size_t)tid * NWG + g], bv);
        astorei(&cand_idx[(size_t)tid * NWG + g], bi);
    }
}

// --------------------------------------------------------- main persistent --
__global__ __launch_bounds__(NTHR, 1)
void seq2seq_persist(
    const int* __restrict__ inputs, const int* __restrict__ lens,
    const float* __restrict__ enc_emb, const float* __restrict__ dec_emb,
    const float* __restrict__ eW0ih, const float* __restrict__ eW0hh,
    const float* __restrict__ eB0ih, const float* __restrict__ eB0hh,
    const float* __restrict__ eW1ih, const float* __restrict__ eW1hh,
    const float* __restrict__ eB1ih, const float* __restrict__ eB1hh,
    const float* __restrict__ dW0ih, const float* __restrict__ dW0hh,
    const float* __restrict__ dB0ih, const float* __restrict__ dB0hh,
    const float* __restrict__ dW1ih, const float* __restrict__ dW1hh,
    const float* __restrict__ dB1ih, const float* __restrict__ dB1hh,
    const float* __restrict__ fcW, const float* __restrict__ fcb,
    float* __restrict__ out,
    float* hb, float* cb, unsigned* flags, unsigned* sense, int fresh)
{
    __shared__ SMem sm;
    const int g = blockIdx.x;
    const int tid = threadIdx.x;
    const int j0 = g * 2;
    unsigned epoch = 0;

    // entry: invalidate cache lines retained from a previous graph replay
    __builtin_amdgcn_fence(__ATOMIC_ACQUIRE, "agent");

    const int wave = tid >> 6, lane = tid & 63, kq16 = lane & 15, bl = lane >> 4;
    const int b = wave * 4 + bl;

    if (tid < 64) {
        astore(&genp(hb, 0, fresh)[g * 64 + tid], 0.f);    // h0e[0]
        astore(&genp(hb, 65, fresh)[g * 64 + tid], 0.f);   // h1e[0]
    }
    stage_w<EDIM>(sm.w0, eW0ih, eW0hh, eB0ih, eB0hh, sm.bsum0, j0);
    stage_w<HDIM>(sm.w1, eW1ih, eW1hh, eB1ih, eB1hh, sm.bsum1, j0);
    if (tid < BSZ) sm.llen[tid] = lens[tid];
    float c0r = 0.f, c1r = 0.f;
    float hold0 = 0.f, hold1 = 0.f;    // per-thread h_old[bb][j] registers
    float hv0c[32], hv1c[32];          // carried per-thread h slices
    gridbar(flags, sense, epoch);

    // ---- encoder: pipelined (cell0(s) || cell1(s-1)), 1 barrier/phase ----
    // gens: h0e[k]=k (0..64), h1e[k]=65+k (65..129)
    for (int s = 0; s <= SLEN; ++s) {
        stage_h(sm.hst, genp(hb, s, fresh), fresh);
        __syncthreads();
        float xv0[16], hv0[32], xv1[32];
        if (s < SLEN) {
            int tokv = inputs[b * SLEN + s];
            const float* x0 = enc_emb + (size_t)tokv * EDIM;
#pragma unroll
            for (int i = 0; i < 4; i++) {
                float4 v = *(const float4*)(x0 + kq16 * 16 + i * 4);
                xv0[i*4] = v.x; xv0[i*4+1] = v.y; xv0[i*4+2] = v.z; xv0[i*4+3] = v.w;
            }
            read_slice32(sm.hst, b, kq16, hv0);
        }
        if (s >= 1) read_slice32(sm.hst, b, kq16, xv1);
        if (s < SLEN)
            cell_compute<EDIM>(sm, sm.w0, sm.bsum0, xv0, hv0,
                               genp(hb, s + 1, fresh), c0r, hold0, true, s, j0, sm.zsh0);
        __syncthreads();
        if (s >= 1) {
            stage_h(sm.hst, genp(hb, 65 + s - 1, fresh), fresh);
            __syncthreads();
            float hv1[32];
            read_slice32(sm.hst, b, kq16, hv1);
            cell_compute<HDIM>(sm, sm.w1, sm.bsum1, xv1, hv1,
                               genp(hb, 65 + s, fresh), c1r, hold1, true, s - 1, j0, sm.zsh1);
        }
        if (s == SLEN) {
#pragma unroll
            for (int i = 0; i < 32; i++) hv0c[i] = xv1[i];  // gen 64 slice = dec h0old
        }
        gridbar(flags, sense, epoch);
    }
    // encoder finals: h0e[64] = gen 64 (carried in hv0c), h1e[64] = gen 129

    // ---- decoder setup: stage dec weights + load fcW into registers ----
    stage_w<EDIM>(sm.w0, dW0ih, dW0hh, dB0ih, dB0hh, sm.bsum0, j0);
    stage_w<HDIM>(sm.w1, dW1ih, dW1hh, dB1ih, dB1hh, sm.bsum1, j0);
    float4 wfc[4][8];
    {
        const int kh = tid & 15, rg = tid >> 4;
        if (g < FCWGS) {
            const float* wp = fcW + ((size_t)g * FCR + rg * 4) * HDIM + kh * 32;
#pragma unroll
            for (int r = 0; r < 4; r++)
#pragma unroll
                for (int i = 0; i < 8; i++)
                    wfc[r][i] = *(const float4*)(wp + (size_t)r * HDIM + i * 4);
            for (int i = tid; i < FCR; i += NTHR) sm.fcb_s[i] = fcb[g * FCR + i];
        }
    }
    c0r = 0.f; c1r = 0.f;
    __syncthreads();

    // gens: h0d out = 130+t, h1d out = 194+t; h1d[0] in = 129
    for (int t = 0; t < TLEN; ++t) {
        const int g0o = 130 + t;
        const int g1o = 194 + t;
        // ---- phase 1: argmax + cell0 (h0old slice carried in hv0c) ----
        if (t == 0) {
            if (tid < BSZ) sm.tok[tid] = 1;
        } else {
            const float* cvp = cb + (size_t)(fresh ? (t - 1) : ((t - 1) & 1)) * HGEN;
            const float* cip = cvp + 8192;
            if (fresh) {
#pragma unroll
                for (int i = 0; i < 4; i++) {
                    int f = i * 2048 + tid * 4;
                    *(float4*)(sm.hst + f) = *(const float4*)(cvp + f);
                    *(float4*)(sm.hst + 8192 + f) = *(const float4*)(cip + f);
                }
            } else {
#pragma unroll
                for (int i = 0; i < 8; i++) {
                    int f = i * 1024 + tid * 2;
                    *(float2*)(sm.hst + f) = aload2(cvp + f);
                    *(float2*)(sm.hst + 8192 + f) = aload2(cip + f);
                }
            }
            __syncthreads();
            if (tid < 256) {
                int bq = tid >> 3, q = tid & 7;
                float bv = -FLT_MAX; int bi = 0x7fffffff;
                for (int gg = q; gg < FCWGS; gg += 8) {
                    float v = sm.hst[bq * 256 + gg];
                    int ix = ((const int*)sm.hst)[8192 + bq * 256 + gg];
                    if (v > bv || (v == bv && ix < bi)) { bv = v; bi = ix; }
                }
#pragma unroll
                for (int m = 1; m < 8; m <<= 1) {
                    float ov = __shfl_xor(bv, m); int oi = __shfl_xor(bi, m);
                    if (ov > bv || (ov == bv && oi < bi)) { bv = ov; bi = oi; }
                }
                if (q == 0) sm.tok[bq] = bi;
            }
        }
        __syncthreads();
        {
            const float* x0 = dec_emb + (size_t)sm.tok[b] * EDIM;
            float xv0[16];
#pragma unroll
            for (int i = 0; i < 4; i++) {
                float4 v = *(const float4*)(x0 + kq16 * 16 + i * 4);
                xv0[i*4] = v.x; xv0[i*4+1] = v.y; xv0[i*4+2] = v.z; xv0[i*4+3] = v.w;
            }
            cell_compute<EDIM>(sm, sm.w0, sm.bsum0, xv0, hv0c,
                               genp(hb, g0o, fresh), c0r, hold0, false, 0, j0, sm.zsh0);
        }
        gridbar(flags, sense, epoch);
        // ---- phase 2: cell1 (x = h0new staged; h1old slice carried) ----
        stage_h(sm.hst, genp(hb, g0o, fresh), fresh);
        __syncthreads();
        float xv1[32];
        read_slice32(sm.hst, b, kq16, xv1);
#pragma unroll
        for (int i = 0; i < 32; i++) hv0c[i] = xv1[i];   // carry for next cell0
        if (t == 0) {
            __syncthreads();
            stage_h(sm.hst, genp(hb, 129, fresh), fresh);   // enc final h1
            __syncthreads();
            read_slice32(sm.hst, b, kq16, hv1c);
        }
        __syncthreads();
        cell_compute<HDIM>(sm, sm.w1, sm.bsum1, xv1, hv1c,
                           genp(hb, g1o, fresh), c1r, hold1, false, 0, j0, sm.zsh1);
        gridbar(flags, sense, epoch);
        // ---- phase 3: stage h1new (all WGs) -> carry + fc ----
        stage_h(sm.hst, genp(hb, g1o, fresh), fresh);
        __syncthreads();
        read_slice32(sm.hst, b, kq16, hv1c);             // carry for next cell1
        if (g < FCWGS) {
            float* cvt = cb + (size_t)(fresh ? t : (t & 1)) * HGEN;
            fc_run(sm, wfc, out, t, g, cvt, (int*)(cvt + 8192));
        }
        if (t < TLEN - 1)
            gridbar(flags, sense, epoch);
    }
}

// ------------------------------------------------------------------- init ---
__global__ void initk(unsigned* flags)
{
    int i = blockIdx.x * 256 + threadIdx.x;
    if (i < NWG * FSTR + 16) flags[i] = 0u;
}

// ----------------------------------------------------------------- driver ---
extern "C" void kernel_launch(void* const* d_in, const int* in_sizes, int n_in,
                              void* d_out, int out_size, void* d_ws, size_t ws_size,
                              hipStream_t stream)
{
    const int*   inputs  = (const int*)d_in[0];
    const int*   lens    = (const int*)d_in[3];
    const float* enc_emb = (const float*)d_in[4];
    const float* dec_emb = (const float*)d_in[5];
    const float* W[16];
    for (int i = 0; i < 16; i++) W[i] = (const float*)d_in[6 + i];
    const float* fcW = (const float*)d_in[22];
    const float* fcb = (const float*)d_in[23];
    float* out = (float*)d_out;

    float* ws = (float*)d_ws;
    unsigned* flags = (unsigned*)ws;                   // 256*16 + sense line
    float* hb = ws + 8192;                             // h generations
    size_t needB = (size_t)(8192 + (NHG_FRESH + NCG_FRESH) * HGEN) * 4;
    int fresh = (ws_size >= needB) ? 1 : 0;
    float* cb = hb + (size_t)(fresh ? NHG_FRESH : NHG_FB) * HGEN;

    initk<<<17, 256, 0, stream>>>(flags);
    seq2seq_persist<<<NWG, NTHR, 0, stream>>>(
        inputs, lens, enc_emb, dec_emb,
        W[0], W[1], W[2], W[3], W[4], W[5], W[6], W[7],
        W[8], W[9], W[10], W[11], W[12], W[13], W[14], W[15],
        fcW, fcb, out,
        hb, cb, flags, flags + NWG * FSTR, fresh);
}

// Round 14
// 4689.465 us; speedup vs baseline: 1.3084x; 1.3076x over previous
//
#include <hip/hip_runtime.h>
#include <cstdint>
#include <cstddef>
#include <cfloat>

// Persistent Seq2Seq LSTM v12 (B=32,S=T=64,E=256,H=512,V=32000), fp32.
// R14 = R10 (proven best: two-level fence-free barrier, fresh-buffer cached
// broadcast, fcW in VGPRs) + DIRECT L2 cell reads:
//   cell-phase h slices are one 128B line per thread -> zero intra-WG reuse
//   -> LDS staging there was pure overhead (2 syncthreads + extra hop per
//   stage). Cells now read gen buffers directly (plain cached; fresh addrs
//   guarantee no stale lines). fc keeps LDS staging (16x reuse). cand keeps
//   staging. NO new live registers vs R10 (R12/R13's spill trap avoided).

#define NWG   256
#define NTHR  512
#define BSZ   32
#define SLEN  64
#define TLEN  64
#define EDIM  256
#define HDIM  512
#define VOUT  32000
#define FCWGS 250
#define FCR   128
#define FSTR  16

#define XS0 20
#define HSL 36
#define RS0 (16 * XS0 + 16 * HSL)
#define RS1 (16 * HSL + 16 * HSL)
#define HB  576
#define HGEN 16384          // floats per h generation (64KB)
#define NHG_FRESH 258
#define NHG_FB    8
#define NCG_FRESH 64
#define NCG_FB    2

struct SMem {
    float w0[8 * RS0];
    float w1[8 * RS1];
    float hst[32 * HB];
    float zsh0[8 * 32];
    float zsh1[8 * 32];
    float cmv[32 * 32];
    int   cmi[32 * 32];
    float bsum0[8], bsum1[8];
    float fcb_s[FCR];
    int   tok[BSZ];
    int   llen[BSZ];
};

// ------------------------------------------------- relaxed agent atomics ----
__device__ __forceinline__ float aload(const float* p) {
    return __hip_atomic_load(p, __ATOMIC_RELAXED, __HIP_MEMORY_SCOPE_AGENT);
}
__device__ __forceinline__ void astore(float* p, float v) {
    __hip_atomic_store(p, v, __ATOMIC_RELAXED, __HIP_MEMORY_SCOPE_AGENT);
}
__device__ __forceinline__ void astorei(int* p, int v) {
    __hip_atomic_store(p, v, __ATOMIC_RELAXED, __HIP_MEMORY_SCOPE_AGENT);
}
__device__ __forceinline__ float2 aload2(const float* p) {
    unsigned long long u = __hip_atomic_load((const unsigned long long*)p,
                              __ATOMIC_RELAXED, __HIP_MEMORY_SCOPE_AGENT);
    union { unsigned long long u; float2 f; } c; c.u = u; return c.f;
}

// -------------------------------------------------- buffer generation map ---
__device__ __forceinline__ int fbmap(int g) {
    if (g < 65)  return (g & 1);
    if (g < 130) return 2 + ((g - 65) & 1);
    if (g < 194) return 4 + ((g - 130) & 1);
    return 6 + ((g - 194) & 1);
}
__device__ __forceinline__ float* genp(float* hb, int g, int fresh) {
    return hb + (size_t)(fresh ? g : fbmap(g)) * HGEN;
}

// ---------------------------------------------------------- grid barrier ----
// Two-level, fence-free (identical to R6/R7/R10 — proven).
__device__ __forceinline__ void gridbar(unsigned* flags, unsigned* sense,
                                        unsigned& epoch)
{
    asm volatile("s_waitcnt vmcnt(0)" ::: "memory");
    __syncthreads();
    epoch++;
    const int tid = threadIdx.x;
    if (tid == 0)
        __hip_atomic_store(&flags[(size_t)blockIdx.x * FSTR], epoch,
                           __ATOMIC_RELAXED, __HIP_MEMORY_SCOPE_AGENT);
    if (blockIdx.x == 0) {
        if (tid < 64) {
#pragma unroll
            for (int k = 0; k < 4; k++) {
                const size_t idx = (size_t)(tid * 4 + k) * FSTR;
                while (__hip_atomic_load(&flags[idx], __ATOMIC_RELAXED,
                                         __HIP_MEMORY_SCOPE_AGENT) < epoch)
                    __builtin_amdgcn_s_sleep(2);
            }
        }
        __syncthreads();
        if (tid == 0)
            __hip_atomic_store(sense, epoch, __ATOMIC_RELAXED,
                               __HIP_MEMORY_SCOPE_AGENT);
    }
    if (tid == 0) {
        while (__hip_atomic_load(sense, __ATOMIC_RELAXED,
                                 __HIP_MEMORY_SCOPE_AGENT) < epoch)
            __builtin_amdgcn_s_sleep(4);
    }
    __syncthreads();
}

// -------------------------------------------- direct per-thread slice read --
// thread (b,kq) owns h[b*512 + kq*32 .. +32] -> one 128B line, 4x float4.
__device__ __forceinline__ void read_gslice(const float* __restrict__ hg,
                                            int b, int kq, float* dst, int cached)
{
    if (cached) {
#pragma unroll
        for (int i = 0; i < 8; i++) {
            float4 v = *(const float4*)(hg + b * HDIM + kq * 32 + i * 4);
            dst[i * 4 + 0] = v.x; dst[i * 4 + 1] = v.y;
            dst[i * 4 + 2] = v.z; dst[i * 4 + 3] = v.w;
        }
    } else {
#pragma unroll
        for (int i = 0; i < 16; i++) {
            float2 v = aload2(hg + b * HDIM + kq * 32 + i * 2);
            dst[i * 2] = v.x; dst[i * 2 + 1] = v.y;
        }
    }
}

// ------------------------------------------------- h staging (fc only) ------
__device__ __forceinline__ void stage_h(float* hst, const float* __restrict__ hg,
                                        int cached)
{
    const int t = threadIdx.x;
    if (cached) {
#pragma unroll
        for (int i = 0; i < 8; i++) {
            int f = i * 2048 + t * 4;
            float4 v = *(const float4*)(hg + f);
            int b = f >> 9, j = f & 511;
            *(float4*)(&hst[b * HB + (j >> 5) * 36 + (j & 31)]) = v;
        }
    } else {
#pragma unroll
        for (int i = 0; i < 16; i++) {
            int f = i * 1024 + t * 2;
            float2 v = aload2(hg + f);
            int b = f >> 9, j = f & 511;
            *(float2*)(&hst[b * HB + (j >> 5) * 36 + (j & 31)]) = v;
        }
    }
}
__device__ __forceinline__ void read_slice32(const float* hst, int b, int kq,
                                             float* dst)
{
#pragma unroll
    for (int i = 0; i < 8; i++) {
        float4 v = *(const float4*)(hst + b * HB + kq * 36 + i * 4);
        dst[i * 4 + 0] = v.x; dst[i * 4 + 1] = v.y;
        dst[i * 4 + 2] = v.z; dst[i * 4 + 3] = v.w;
    }
}

// ------------------------------------------------------- weight staging -----
template<int KIN>
__device__ __forceinline__ void stage_w(float* dst,
        const float* __restrict__ Wih, const float* __restrict__ Whh,
        const float* __restrict__ bih, const float* __restrict__ bhh,
        float* bsum, int j0)
{
    constexpr int XC = KIN / 16;
    constexpr int XS = (KIN == 256) ? XS0 : HSL;
    constexpr int RS = (KIN == 256) ? RS0 : RS1;
    const int tid = threadIdx.x;
    constexpr int nf4x = KIN / 4;
    for (int tt = tid; tt < 8 * nf4x; tt += NTHR) {
        int r = tt / nf4x, k = (tt % nf4x) * 4;
        int row = (r >> 1) * HDIM + j0 + (r & 1);
        float4 v = *(const float4*)(Wih + (size_t)row * KIN + k);
        *(float4*)(dst + r * RS + (k / XC) * XS + (k % XC)) = v;
    }
    for (int tt = tid; tt < 8 * 128; tt += NTHR) {
        int r = tt >> 7, k = (tt & 127) * 4;
        int row = (r >> 1) * HDIM + j0 + (r & 1);
        float4 v = *(const float4*)(Whh + (size_t)row * HDIM + k);
        *(float4*)(dst + r * RS + 16 * XS + (k >> 5) * HSL + (k & 31)) = v;
    }
    if (tid < 8) {
        int row = (tid >> 1) * HDIM + j0 + (tid & 1);
        bsum[tid] = bih[row] + bhh[row];
    }
}

// ------------------------------------------------------------- LSTM cell ----
// Masked old-h read directly from the input generation buffer (hin_g).
template<int KIN>
__device__ __forceinline__ void cell_compute(SMem& sm, const float* __restrict__ w,
        const float* bsum, const float* xv, const float* hv,
        const float* __restrict__ hin_g, float* __restrict__ hout,
        float& creg, bool domask, int s, int j0, float* zsh, int cached)
{
    constexpr int XC = KIN / 16;
    constexpr int XS = (KIN == 256) ? XS0 : HSL;
    constexpr int RS = (KIN == 256) ? RS0 : RS1;
    const int tid = threadIdx.x;
    const int wave = tid >> 6, lane = tid & 63, kq = lane & 15, bl = lane >> 4;
    const int b = wave * 4 + bl;

#pragma unroll
    for (int r = 0; r < 8; r++) {
        float acc = 0.f;
        const float* wx = w + r * RS + kq * XS;
#pragma unroll
        for (int i = 0; i < XC / 4; i++) {
            float4 t4 = *(const float4*)(wx + i * 4);
            acc += t4.x * xv[i*4] + t4.y * xv[i*4+1] + t4.z * xv[i*4+2] + t4.w * xv[i*4+3];
        }
        const float* wh = w + r * RS + 16 * XS + kq * HSL;
#pragma unroll
        for (int i = 0; i < 8; i++) {
            float4 t4 = *(const float4*)(wh + i * 4);
            acc += t4.x * hv[i*4] + t4.y * hv[i*4+1] + t4.z * hv[i*4+2] + t4.w * hv[i*4+3];
        }
        acc += __shfl_xor(acc, 1);
        acc += __shfl_xor(acc, 2);
        acc += __shfl_xor(acc, 4);
        acc += __shfl_xor(acc, 8);
        if (kq == 0) zsh[r * 32 + b] = acc + bsum[r];
    }
    __syncthreads();
    if (tid < 64) {
        int jl = tid >> 5, bb = tid & 31;
        float zi = zsh[(0 + jl) * 32 + bb];
        float zf = zsh[(2 + jl) * 32 + bb];
        float zg = zsh[(4 + jl) * 32 + bb];
        float zo = zsh[(6 + jl) * 32 + bb];
        float iv = 1.f / (1.f + expf(-zi));
        float fv = 1.f / (1.f + expf(-zf));
        float gv = tanhf(zg);
        float ov = 1.f / (1.f + expf(-zo));
        float cold = creg;
        float c2 = fv * cold + iv * gv;
        float h2 = ov * tanhf(c2);
        int j = j0 + jl;
        if (domask) {
            bool m = s < sm.llen[bb];
            if (!m) {
                size_t off = (size_t)bb * HDIM + j;
                h2 = cached ? hin_g[off] : aload(hin_g + off);
                c2 = cold;
            }
        }
        astore(hout + (size_t)bb * HDIM + j, h2);
        creg = c2;
    }
}

// ------------------------------------------------- fc (weights in VGPRs) ----
__device__ __forceinline__ void fc_run(SMem& sm, const float4 (&wfc)[4][8],
        const float* __restrict__ h1g, float* __restrict__ out, int t, int g,
        float* __restrict__ cand_val, int* __restrict__ cand_idx, int cached)
{
    const int tid = threadIdx.x;
    const int kh = tid & 15, rg = tid >> 4;
    const int v0 = g * FCR;

    stage_h(sm.hst, h1g, cached);
    __syncthreads();

    float bias[4];
#pragma unroll
    for (int r = 0; r < 4; r++) bias[r] = sm.fcb_s[rg * 4 + r];

    for (int b = 0; b < 32; b++) {
        float hv[32];
        read_slice32(sm.hst, b, kh, hv);
        float a0 = 0.f, a1 = 0.f, a2 = 0.f, a3 = 0.f;
#pragma unroll
        for (int i = 0; i < 8; i++) {
            float4 w0 = wfc[0][i], w1 = wfc[1][i], w2 = wfc[2][i], w3 = wfc[3][i];
            float h0 = hv[i*4], h1 = hv[i*4+1], h2 = hv[i*4+2], h3 = hv[i*4+3];
            a0 += w0.x * h0 + w0.y * h1 + w0.z * h2 + w0.w * h3;
            a1 += w1.x * h0 + w1.y * h1 + w1.z * h2 + w1.w * h3;
            a2 += w2.x * h0 + w2.y * h1 + w2.z * h2 + w2.w * h3;
            a3 += w3.x * h0 + w3.y * h1 + w3.z * h2 + w3.w * h3;
        }
#pragma unroll
        for (int m = 1; m < 16; m <<= 1) {
            a0 += __shfl_xor(a0, m);
            a1 += __shfl_xor(a1, m);
            a2 += __shfl_xor(a2, m);
            a3 += __shfl_xor(a3, m);
        }
        if (kh == 0) {
            float z0 = a0 + bias[0], z1 = a1 + bias[1];
            float z2 = a2 + bias[2], z3 = a3 + bias[3];
            *(float4*)(out + ((size_t)b * TLEN + t) * VOUT + v0 + rg * 4)
                = make_float4(z0, z1, z2, z3);
            float lm = z0; int li = 0;                 // ascending r: strict >
            if (z1 > lm) { lm = z1; li = 1; }
            if (z2 > lm) { lm = z2; li = 2; }
            if (z3 > lm) { lm = z3; li = 3; }
            sm.cmv[rg * 32 + b] = lm;
            sm.cmi[rg * 32 + b] = v0 + rg * 4 + li;
        }
    }
    __syncthreads();
    if (tid < 32) {
        float bv = sm.cmv[tid]; int bi = sm.cmi[tid];
#pragma unroll
        for (int r2 = 1; r2 < 32; r2++) {
            float v = sm.cmv[r2 * 32 + tid]; int ix = sm.cmi[r2 * 32 + tid];
            if (v > bv || (v == bv && ix < bi)) { bv = v; bi = ix; }
        }
        astore(&cand_val[(size_t)tid * NWG + g], bv);
        astorei(&cand_idx[(size_t)tid * NWG + g], bi);
    }
}

// --------------------------------------------------------- main persistent --
__global__ __launch_bounds__(NTHR, 2)
void seq2seq_persist(
    const int* __restrict__ inputs, const int* __restrict__ lens,
    const float* __restrict__ enc_emb, const float* __restrict__ dec_emb,
    const float* __restrict__ eW0ih, const float* __restrict__ eW0hh,
    const float* __restrict__ eB0ih, const float* __restrict__ eB0hh,
    const float* __restrict__ eW1ih, const float* __restrict__ eW1hh,
    const float* __restrict__ eB1ih, const float* __restrict__ eB1hh,
    const float* __restrict__ dW0ih, const float* __restrict__ dW0hh,
    const float* __restrict__ dB0ih, const float* __restrict__ dB0hh,
    const float* __restrict__ dW1ih, const float* __restrict__ dW1hh,
    const float* __restrict__ dB1ih, const float* __restrict__ dB1hh,
    const float* __restrict__ fcW, const float* __restrict__ fcb,
    float* __restrict__ out,
    float* hb, float* cb, unsigned* flags, unsigned* sense, int fresh)
{
    __shared__ SMem sm;
    const int g = blockIdx.x;
    const int tid = threadIdx.x;
    const int j0 = g * 2;
    unsigned epoch = 0;

    // entry: invalidate cache lines retained from a previous graph replay
    __builtin_amdgcn_fence(__ATOMIC_ACQUIRE, "agent");

    const int wave = tid >> 6, lane = tid & 63, kq16 = lane & 15, bl = lane >> 4;
    const int b = wave * 4 + bl;

    if (tid < 64) {
        astore(&genp(hb, 0, fresh)[g * 64 + tid], 0.f);    // h0e[0]
        astore(&genp(hb, 65, fresh)[g * 64 + tid], 0.f);   // h1e[0]
    }
    stage_w<EDIM>(sm.w0, eW0ih, eW0hh, eB0ih, eB0hh, sm.bsum0, j0);
    stage_w<HDIM>(sm.w1, eW1ih, eW1hh, eB1ih, eB1hh, sm.bsum1, j0);
    if (tid < BSZ) sm.llen[tid] = lens[tid];
    float c0r = 0.f, c1r = 0.f;
    gridbar(flags, sense, epoch);

    // ---- encoder: pipelined (cell0(s) || cell1(s-1)), 1 barrier/phase ----
    // gens: h0e[k]=k (0..64), h1e[k]=65+k (65..129)
    for (int s = 0; s <= SLEN; ++s) {
        const float* g0 = genp(hb, s, fresh);
        float hv0[32];                       // slice of h0[s]: cell0 hin = cell1 x
        read_gslice(g0, b, kq16, hv0, fresh);
        if (s < SLEN) {
            int tokv = inputs[b * SLEN + s];
            const float* x0 = enc_emb + (size_t)tokv * EDIM;
            float xv0[16];
#pragma unroll
            for (int i = 0; i < 4; i++) {
                float4 v = *(const float4*)(x0 + kq16 * 16 + i * 4);
                xv0[i*4] = v.x; xv0[i*4+1] = v.y; xv0[i*4+2] = v.z; xv0[i*4+3] = v.w;
            }
            cell_compute<EDIM>(sm, sm.w0, sm.bsum0, xv0, hv0, g0,
                               genp(hb, s + 1, fresh), c0r, true, s, j0,
                               sm.zsh0, fresh);
        }
        if (s >= 1) {
            const float* g1 = genp(hb, 65 + s - 1, fresh);
            float hv1[32];
            read_gslice(g1, b, kq16, hv1, fresh);
            cell_compute<HDIM>(sm, sm.w1, sm.bsum1, hv0, hv1, g1,
                               genp(hb, 65 + s, fresh), c1r, true, s - 1, j0,
                               sm.zsh1, fresh);
        }
        gridbar(flags, sense, epoch);
    }
    // encoder finals: h0e[64] = gen 64, h1e[64] = gen 129

    // ---- decoder setup: stage dec weights + load fcW into registers ----
    stage_w<EDIM>(sm.w0, dW0ih, dW0hh, dB0ih, dB0hh, sm.bsum0, j0);
    stage_w<HDIM>(sm.w1, dW1ih, dW1hh, dB1ih, dB1hh, sm.bsum1, j0);
    float4 wfc[4][8];
    {
        const int kh = tid & 15, rg = tid >> 4;
        if (g < FCWGS) {
            const float* wp = fcW + ((size_t)g * FCR + rg * 4) * HDIM + kh * 32;
#pragma unroll
            for (int r = 0; r < 4; r++)
#pragma unroll
                for (int i = 0; i < 8; i++)
                    wfc[r][i] = *(const float4*)(wp + (size_t)r * HDIM + i * 4);
            for (int i = tid; i < FCR; i += NTHR) sm.fcb_s[i] = fcb[g * FCR + i];
        }
    }
    c0r = 0.f; c1r = 0.f;
    __syncthreads();

    // gens: h0d in = (t==0?64:129+t), out = 130+t; h1d in = (t==0?129:193+t),
    //       out = 194+t
    for (int t = 0; t < TLEN; ++t) {
        const int g0i = (t == 0) ? 64 : 129 + t;
        const int g0o = 130 + t;
        const int g1i = (t == 0) ? 129 : 193 + t;
        const int g1o = 194 + t;
        // ---- phase 1: argmax + cell0 (hin slice read direct) ----
        if (t == 0) {
            if (tid < BSZ) sm.tok[tid] = 1;
        } else {
            const float* cvp = cb + (size_t)(fresh ? (t - 1) : ((t - 1) & 1)) * HGEN;
            const float* cip = cvp + 8192;
            if (fresh) {
#pragma unroll
                for (int i = 0; i < 4; i++) {
                    int f = i * 2048 + tid * 4;
                    *(float4*)(sm.hst + f) = *(const float4*)(cvp + f);
                    *(float4*)(sm.hst + 8192 + f) = *(const float4*)(cip + f);
                }
            } else {
#pragma unroll
                for (int i = 0; i < 8; i++) {
                    int f = i * 1024 + tid * 2;
                    *(float2*)(sm.hst + f) = aload2(cvp + f);
                    *(float2*)(sm.hst + 8192 + f) = aload2(cip + f);
                }
            }
            __syncthreads();
            if (tid < 256) {
                int bq = tid >> 3, q = tid & 7;
                float bv = -FLT_MAX; int bi = 0x7fffffff;
                for (int gg = q; gg < FCWGS; gg += 8) {
                    float v = sm.hst[bq * 256 + gg];
                    int ix = ((const int*)sm.hst)[8192 + bq * 256 + gg];
                    if (v > bv || (v == bv && ix < bi)) { bv = v; bi = ix; }
                }
#pragma unroll
                for (int m = 1; m < 8; m <<= 1) {
                    float ov = __shfl_xor(bv, m); int oi = __shfl_xor(bi, m);
                    if (ov > bv || (ov == bv && oi < bi)) { bv = ov; bi = oi; }
                }
                if (q == 0) sm.tok[bq] = bi;
            }
        }
        __syncthreads();
        {
            const float* x0 = dec_emb + (size_t)sm.tok[b] * EDIM;
            float xv0[16], hv0[32];
#pragma unroll
            for (int i = 0; i < 4; i++) {
                float4 v = *(const float4*)(x0 + kq16 * 16 + i * 4);
                xv0[i*4] = v.x; xv0[i*4+1] = v.y; xv0[i*4+2] = v.z; xv0[i*4+3] = v.w;
            }
            read_gslice(genp(hb, g0i, fresh), b, kq16, hv0, fresh);
            cell_compute<EDIM>(sm, sm.w0, sm.bsum0, xv0, hv0,
                               genp(hb, g0i, fresh), genp(hb, g0o, fresh),
                               c0r, false, 0, j0, sm.zsh0, fresh);
        }
        gridbar(flags, sense, epoch);
        // ---- phase 2: cell1 (x = h0new, hin = h1old; both direct) ----
        {
            float xv1[32], hv1[32];
            read_gslice(genp(hb, g0o, fresh), b, kq16, xv1, fresh);
            read_gslice(genp(hb, g1i, fresh), b, kq16, hv1, fresh);
            cell_compute<HDIM>(sm, sm.w1, sm.bsum1, xv1, hv1,
                               genp(hb, g1i, fresh), genp(hb, g1o, fresh),
                               c1r, false, 0, j0, sm.zsh1, fresh);
        }
        gridbar(flags, sense, epoch);
        // ---- phase 3: fc (stages h1new into LDS: 16x intra-WG reuse) ----
        if (g < FCWGS) {
            float* cvt = cb + (size_t)(fresh ? t : (t & 1)) * HGEN;
            fc_run(sm, wfc, genp(hb, g1o, fresh), out, t, g,
                   cvt, (int*)(cvt + 8192), fresh);
        }
        if (t < TLEN - 1)
            gridbar(flags, sense, epoch);
    }
}

// ------------------------------------------------------------------- init ---
__global__ void initk(unsigned* flags)
{
    int i = blockIdx.x * 256 + threadIdx.x;
    if (i < NWG * FSTR + 16) flags[i] = 0u;
}

// ----------------------------------------------------------------- driver ---
extern "C" void kernel_launch(void* const* d_in, const int* in_sizes, int n_in,
                              void* d_out, int out_size, void* d_ws, size_t ws_size,
                              hipStream_t stream)
{
    const int*   inputs  = (const int*)d_in[0];
    const int*   lens    = (const int*)d_in[3];
    const float* enc_emb = (const float*)d_in[4];
    const float* dec_emb = (const float*)d_in[5];
    const float* W[16];
    for (int i = 0; i < 16; i++) W[i] = (const float*)d_in[6 + i];
    const float* fcW = (const float*)d_in[22];
    const float* fcb = (const float*)d_in[23];
    float* out = (float*)d_out;

    float* ws = (float*)d_ws;
    unsigned* flags = (unsigned*)ws;                   // 256*16 + sense line
    float* hb = ws + 8192;                             // h generations
    size_t needB = (size_t)(8192 + (NHG_FRESH + NCG_FRESH) * HGEN) * 4;
    int fresh = (ws_size >= needB) ? 1 : 0;
    float* cb = hb + (size_t)(fresh ? NHG_FRESH : NHG_FB) * HGEN;

    initk<<<17, 256, 0, stream>>>(flags);
    seq2seq_persist<<<NWG, NTHR, 0, stream>>>(
        inputs, lens, enc_emb, dec_emb,
        W[0], W[1], W[2], W[3], W[4], W[5], W[6], W[7],
        W[8], W[9], W[10], W[11], W[12], W[13], W[14], W[15],
        fcW, fcb, out,
        hb, cb, flags, flags + NWG * FSTR, fresh);
}

// Round 15
// 4455.170 us; speedup vs baseline: 1.3773x; 1.0526x over previous
//
#include <hip/hip_runtime.h>
#include <cstdint>
#include <cstddef>
#include <cfloat>

// Persistent Seq2Seq LSTM v13 (B=32,S=T=64,E=256,H=512,V=32000), fp32.
// R15 = R14 (direct L2 cell reads, fc-in-VGPR, fresh-buffer broadcast) with
// ONE change: the grid barrier.
//  - 256 pollers x 1 flag each (was 64 x 4 serial): discovery ~1 LLC RTT.
//  - aggregator ROTATES (epoch & 255): WG0 no longer the permanent straggler
//    (aggregation+skew penalty was compounding on WG0 every phase).
// Model: residual = 3.1ms/257 phases = 12us/barrier; handshake should be ~5.

#define NWG   256
#define NTHR  512
#define BSZ   32
#define SLEN  64
#define TLEN  64
#define EDIM  256
#define HDIM  512
#define VOUT  32000
#define FCWGS 250
#define FCR   128
#define FSTR  16

#define XS0 20
#define HSL 36
#define RS0 (16 * XS0 + 16 * HSL)
#define RS1 (16 * HSL + 16 * HSL)
#define HB  576
#define HGEN 16384          // floats per h generation (64KB)
#define NHG_FRESH 258
#define NHG_FB    8
#define NCG_FRESH 64
#define NCG_FB    2

struct SMem {
    float w0[8 * RS0];
    float w1[8 * RS1];
    float hst[32 * HB];
    float zsh0[8 * 32];
    float zsh1[8 * 32];
    float cmv[32 * 32];
    int   cmi[32 * 32];
    float bsum0[8], bsum1[8];
    float fcb_s[FCR];
    int   tok[BSZ];
    int   llen[BSZ];
};

// ------------------------------------------------- relaxed agent atomics ----
__device__ __forceinline__ float aload(const float* p) {
    return __hip_atomic_load(p, __ATOMIC_RELAXED, __HIP_MEMORY_SCOPE_AGENT);
}
__device__ __forceinline__ void astore(float* p, float v) {
    __hip_atomic_store(p, v, __ATOMIC_RELAXED, __HIP_MEMORY_SCOPE_AGENT);
}
__device__ __forceinline__ void astorei(int* p, int v) {
    __hip_atomic_store(p, v, __ATOMIC_RELAXED, __HIP_MEMORY_SCOPE_AGENT);
}
__device__ __forceinline__ float2 aload2(const float* p) {
    unsigned long long u = __hip_atomic_load((const unsigned long long*)p,
                              __ATOMIC_RELAXED, __HIP_MEMORY_SCOPE_AGENT);
    union { unsigned long long u; float2 f; } c; c.u = u; return c.f;
}

// -------------------------------------------------- buffer generation map ---
__device__ __forceinline__ int fbmap(int g) {
    if (g < 65)  return (g & 1);
    if (g < 130) return 2 + ((g - 65) & 1);
    if (g < 194) return 4 + ((g - 130) & 1);
    return 6 + ((g - 194) & 1);
}
__device__ __forceinline__ float* genp(float* hb, int g, int fresh) {
    return hb + (size_t)(fresh ? g : fbmap(g)) * HGEN;
}

// ---------------------------------------------------------- grid barrier ----
// Two-level, fence-free; v2: 256 pollers x 1 flag, rotating aggregator.
__device__ __forceinline__ void gridbar(unsigned* flags, unsigned* sense,
                                        unsigned& epoch)
{
    asm volatile("s_waitcnt vmcnt(0)" ::: "memory");
    __syncthreads();
    epoch++;
    const int tid = threadIdx.x;
    if (tid == 0)
        __hip_atomic_store(&flags[(size_t)blockIdx.x * FSTR], epoch,
                           __ATOMIC_RELAXED, __HIP_MEMORY_SCOPE_AGENT);
    if (blockIdx.x == (int)(epoch & (NWG - 1))) {     // rotating aggregator
        if (tid < NWG) {
            while (__hip_atomic_load(&flags[(size_t)tid * FSTR],
                                     __ATOMIC_RELAXED,
                                     __HIP_MEMORY_SCOPE_AGENT) < epoch)
                __builtin_amdgcn_s_sleep(1);
        }
        __syncthreads();
        if (tid == 0)
            __hip_atomic_store(sense, epoch, __ATOMIC_RELAXED,
                               __HIP_MEMORY_SCOPE_AGENT);
    }
    if (tid == 0) {
        while (__hip_atomic_load(sense, __ATOMIC_RELAXED,
                                 __HIP_MEMORY_SCOPE_AGENT) < epoch)
            __builtin_amdgcn_s_sleep(2);
    }
    __syncthreads();
}

// -------------------------------------------- direct per-thread slice read --
// thread (b,kq) owns h[b*512 + kq*32 .. +32] -> one 128B line, 4x float4.
__device__ __forceinline__ void read_gslice(const float* __restrict__ hg,
                                            int b, int kq, float* dst, int cached)
{
    if (cached) {
#pragma unroll
        for (int i = 0; i < 8; i++) {
            float4 v = *(const float4*)(hg + b * HDIM + kq * 32 + i * 4);
            dst[i * 4 + 0] = v.x; dst[i * 4 + 1] = v.y;
            dst[i * 4 + 2] = v.z; dst[i * 4 + 3] = v.w;
        }
    } else {
#pragma unroll
        for (int i = 0; i < 16; i++) {
            float2 v = aload2(hg + b * HDIM + kq * 32 + i * 2);
            dst[i * 2] = v.x; dst[i * 2 + 1] = v.y;
        }
    }
}

// ------------------------------------------------- h staging (fc only) ------
__device__ __forceinline__ void stage_h(float* hst, const float* __restrict__ hg,
                                        int cached)
{
    const int t = threadIdx.x;
    if (cached) {
#pragma unroll
        for (int i = 0; i < 8; i++) {
            int f = i * 2048 + t * 4;
            float4 v = *(const float4*)(hg + f);
            int b = f >> 9, j = f & 511;
            *(float4*)(&hst[b * HB + (j >> 5) * 36 + (j & 31)]) = v;
        }
    } else {
#pragma unroll
        for (int i = 0; i < 16; i++) {
            int f = i * 1024 + t * 2;
            float2 v = aload2(hg + f);
            int b = f >> 9, j = f & 511;
            *(float2*)(&hst[b * HB + (j >> 5) * 36 + (j & 31)]) = v;
        }
    }
}
__device__ __forceinline__ void read_slice32(const float* hst, int b, int kq,
                                             float* dst)
{
#pragma unroll
    for (int i = 0; i < 8; i++) {
        float4 v = *(const float4*)(hst + b * HB + kq * 36 + i * 4);
        dst[i * 4 + 0] = v.x; dst[i * 4 + 1] = v.y;
        dst[i * 4 + 2] = v.z; dst[i * 4 + 3] = v.w;
    }
}

// ------------------------------------------------------- weight staging -----
template<int KIN>
__device__ __forceinline__ void stage_w(float* dst,
        const float* __restrict__ Wih, const float* __restrict__ Whh,
        const float* __restrict__ bih, const float* __restrict__ bhh,
        float* bsum, int j0)
{
    constexpr int XC = KIN / 16;
    constexpr int XS = (KIN == 256) ? XS0 : HSL;
    constexpr int RS = (KIN == 256) ? RS0 : RS1;
    const int tid = threadIdx.x;
    constexpr int nf4x = KIN / 4;
    for (int tt = tid; tt < 8 * nf4x; tt += NTHR) {
        int r = tt / nf4x, k = (tt % nf4x) * 4;
        int row = (r >> 1) * HDIM + j0 + (r & 1);
        float4 v = *(const float4*)(Wih + (size_t)row * KIN + k);
        *(float4*)(dst + r * RS + (k / XC) * XS + (k % XC)) = v;
    }
    for (int tt = tid; tt < 8 * 128; tt += NTHR) {
        int r = tt >> 7, k = (tt & 127) * 4;
        int row = (r >> 1) * HDIM + j0 + (r & 1);
        float4 v = *(const float4*)(Whh + (size_t)row * HDIM + k);
        *(float4*)(dst + r * RS + 16 * XS + (k >> 5) * HSL + (k & 31)) = v;
    }
    if (tid < 8) {
        int row = (tid >> 1) * HDIM + j0 + (tid & 1);
        bsum[tid] = bih[row] + bhh[row];
    }
}

// ------------------------------------------------------------- LSTM cell ----
// Masked old-h read directly from the input generation buffer (hin_g).
template<int KIN>
__device__ __forceinline__ void cell_compute(SMem& sm, const float* __restrict__ w,
        const float* bsum, const float* xv, const float* hv,
        const float* __restrict__ hin_g, float* __restrict__ hout,
        float& creg, bool domask, int s, int j0, float* zsh, int cached)
{
    constexpr int XC = KIN / 16;
    constexpr int XS = (KIN == 256) ? XS0 : HSL;
    constexpr int RS = (KIN == 256) ? RS0 : RS1;
    const int tid = threadIdx.x;
    const int wave = tid >> 6, lane = tid & 63, kq = lane & 15, bl = lane >> 4;
    const int b = wave * 4 + bl;

#pragma unroll
    for (int r = 0; r < 8; r++) {
        float acc = 0.f;
        const float* wx = w + r * RS + kq * XS;
#pragma unroll
        for (int i = 0; i < XC / 4; i++) {
            float4 t4 = *(const float4*)(wx + i * 4);
            acc += t4.x * xv[i*4] + t4.y * xv[i*4+1] + t4.z * xv[i*4+2] + t4.w * xv[i*4+3];
        }
        const float* wh = w + r * RS + 16 * XS + kq * HSL;
#pragma unroll
        for (int i = 0; i < 8; i++) {
            float4 t4 = *(const float4*)(wh + i * 4);
            acc += t4.x * hv[i*4] + t4.y * hv[i*4+1] + t4.z * hv[i*4+2] + t4.w * hv[i*4+3];
        }
        acc += __shfl_xor(acc, 1);
        acc += __shfl_xor(acc, 2);
        acc += __shfl_xor(acc, 4);
        acc += __shfl_xor(acc, 8);
        if (kq == 0) zsh[r * 32 + b] = acc + bsum[r];
    }
    __syncthreads();
    if (tid < 64) {
        int jl = tid >> 5, bb = tid & 31;
        float zi = zsh[(0 + jl) * 32 + bb];
        float zf = zsh[(2 + jl) * 32 + bb];
        float zg = zsh[(4 + jl) * 32 + bb];
        float zo = zsh[(6 + jl) * 32 + bb];
        float iv = 1.f / (1.f + expf(-zi));
        float fv = 1.f / (1.f + expf(-zf));
        float gv = tanhf(zg);
        float ov = 1.f / (1.f + expf(-zo));
        float cold = creg;
        float c2 = fv * cold + iv * gv;
        float h2 = ov * tanhf(c2);
        int j = j0 + jl;
        if (domask) {
            bool m = s < sm.llen[bb];
            if (!m) {
                size_t off = (size_t)bb * HDIM + j;
                h2 = cached ? hin_g[off] : aload(hin_g + off);
                c2 = cold;
            }
        }
        astore(hout + (size_t)bb * HDIM + j, h2);
        creg = c2;
    }
}

// ------------------------------------------------- fc (weights in VGPRs) ----
__device__ __forceinline__ void fc_run(SMem& sm, const float4 (&wfc)[4][8],
        const float* __restrict__ h1g, float* __restrict__ out, int t, int g,
        float* __restrict__ cand_val, int* __restrict__ cand_idx, int cached)
{
    const int tid = threadIdx.x;
    const int kh = tid & 15, rg = tid >> 4;
    const int v0 = g * FCR;

    stage_h(sm.hst, h1g, cached);
    __syncthreads();

    float bias[4];
#pragma unroll
    for (int r = 0; r < 4; r++) bias[r] = sm.fcb_s[rg * 4 + r];

    for (int b = 0; b < 32; b++) {
        float hv[32];
        read_slice32(sm.hst, b, kh, hv);
        float a0 = 0.f, a1 = 0.f, a2 = 0.f, a3 = 0.f;
#pragma unroll
        for (int i = 0; i < 8; i++) {
            float4 w0 = wfc[0][i], w1 = wfc[1][i], w2 = wfc[2][i], w3 = wfc[3][i];
            float h0 = hv[i*4], h1 = hv[i*4+1], h2 = hv[i*4+2], h3 = hv[i*4+3];
            a0 += w0.x * h0 + w0.y * h1 + w0.z * h2 + w0.w * h3;
            a1 += w1.x * h0 + w1.y * h1 + w1.z * h2 + w1.w * h3;
            a2 += w2.x * h0 + w2.y * h1 + w2.z * h2 + w2.w * h3;
            a3 += w3.x * h0 + w3.y * h1 + w3.z * h2 + w3.w * h3;
        }
#pragma unroll
        for (int m = 1; m < 16; m <<= 1) {
            a0 += __shfl_xor(a0, m);
            a1 += __shfl_xor(a1, m);
            a2 += __shfl_xor(a2, m);
            a3 += __shfl_xor(a3, m);
        }
        if (kh == 0) {
            float z0 = a0 + bias[0], z1 = a1 + bias[1];
            float z2 = a2 + bias[2], z3 = a3 + bias[3];
            *(float4*)(out + ((size_t)b * TLEN + t) * VOUT + v0 + rg * 4)
                = make_float4(z0, z1, z2, z3);
            float lm = z0; int li = 0;                 // ascending r: strict >
            if (z1 > lm) { lm = z1; li = 1; }
            if (z2 > lm) { lm = z2; li = 2; }
            if (z3 > lm) { lm = z3; li = 3; }
            sm.cmv[rg * 32 + b] = lm;
            sm.cmi[rg * 32 + b] = v0 + rg * 4 + li;
        }
    }
    __syncthreads();
    if (tid < 32) {
        float bv = sm.cmv[tid]; int bi = sm.cmi[tid];
#pragma unroll
        for (int r2 = 1; r2 < 32; r2++) {
            float v = sm.cmv[r2 * 32 + tid]; int ix = sm.cmi[r2 * 32 + tid];
            if (v > bv || (v == bv && ix < bi)) { bv = v; bi = ix; }
        }
        astore(&cand_val[(size_t)tid * NWG + g], bv);
        astorei(&cand_idx[(size_t)tid * NWG + g], bi);
    }
}

// --------------------------------------------------------- main persistent --
__global__ __launch_bounds__(NTHR, 2)
void seq2seq_persist(
    const int* __restrict__ inputs, const int* __restrict__ lens,
    const float* __restrict__ enc_emb, const float* __restrict__ dec_emb,
    const float* __restrict__ eW0ih, const float* __restrict__ eW0hh,
    const float* __restrict__ eB0ih, const float* __restrict__ eB0hh,
    const float* __restrict__ eW1ih, const float* __restrict__ eW1hh,
    const float* __restrict__ eB1ih, const float* __restrict__ eB1hh,
    const float* __restrict__ dW0ih, const float* __restrict__ dW0hh,
    const float* __restrict__ dB0ih, const float* __restrict__ dB0hh,
    const float* __restrict__ dW1ih, const float* __restrict__ dW1hh,
    const float* __restrict__ dB1ih, const float* __restrict__ dB1hh,
    const float* __restrict__ fcW, const float* __restrict__ fcb,
    float* __restrict__ out,
    float* hb, float* cb, unsigned* flags, unsigned* sense, int fresh)
{
    __shared__ SMem sm;
    const int g = blockIdx.x;
    const int tid = threadIdx.x;
    const int j0 = g * 2;
    unsigned epoch = 0;

    // entry: invalidate cache lines retained from a previous graph replay
    __builtin_amdgcn_fence(__ATOMIC_ACQUIRE, "agent");

    const int wave = tid >> 6, lane = tid & 63, kq16 = lane & 15, bl = lane >> 4;
    const int b = wave * 4 + bl;

    if (tid < 64) {
        astore(&genp(hb, 0, fresh)[g * 64 + tid], 0.f);    // h0e[0]
        astore(&genp(hb, 65, fresh)[g * 64 + tid], 0.f);   // h1e[0]
    }
    stage_w<EDIM>(sm.w0, eW0ih, eW0hh, eB0ih, eB0hh, sm.bsum0, j0);
    stage_w<HDIM>(sm.w1, eW1ih, eW1hh, eB1ih, eB1hh, sm.bsum1, j0);
    if (tid < BSZ) sm.llen[tid] = lens[tid];
    float c0r = 0.f, c1r = 0.f;
    gridbar(flags, sense, epoch);

    // ---- encoder: pipelined (cell0(s) || cell1(s-1)), 1 barrier/phase ----
    // gens: h0e[k]=k (0..64), h1e[k]=65+k (65..129)
    for (int s = 0; s <= SLEN; ++s) {
        const float* g0 = genp(hb, s, fresh);
        float hv0[32];                       // slice of h0[s]: cell0 hin = cell1 x
        read_gslice(g0, b, kq16, hv0, fresh);
        if (s < SLEN) {
            int tokv = inputs[b * SLEN + s];
            const float* x0 = enc_emb + (size_t)tokv * EDIM;
            float xv0[16];
#pragma unroll
            for (int i = 0; i < 4; i++) {
                float4 v = *(const float4*)(x0 + kq16 * 16 + i * 4);
                xv0[i*4] = v.x; xv0[i*4+1] = v.y; xv0[i*4+2] = v.z; xv0[i*4+3] = v.w;
            }
            cell_compute<EDIM>(sm, sm.w0, sm.bsum0, xv0, hv0, g0,
                               genp(hb, s + 1, fresh), c0r, true, s, j0,
                               sm.zsh0, fresh);
        }
        if (s >= 1) {
            const float* g1 = genp(hb, 65 + s - 1, fresh);
            float hv1[32];
            read_gslice(g1, b, kq16, hv1, fresh);
            cell_compute<HDIM>(sm, sm.w1, sm.bsum1, hv0, hv1, g1,
                               genp(hb, 65 + s, fresh), c1r, true, s - 1, j0,
                               sm.zsh1, fresh);
        }
        gridbar(flags, sense, epoch);
    }
    // encoder finals: h0e[64] = gen 64, h1e[64] = gen 129

    // ---- decoder setup: stage dec weights + load fcW into registers ----
    stage_w<EDIM>(sm.w0, dW0ih, dW0hh, dB0ih, dB0hh, sm.bsum0, j0);
    stage_w<HDIM>(sm.w1, dW1ih, dW1hh, dB1ih, dB1hh, sm.bsum1, j0);
    float4 wfc[4][8];
    {
        const int kh = tid & 15, rg = tid >> 4;
        if (g < FCWGS) {
            const float* wp = fcW + ((size_t)g * FCR + rg * 4) * HDIM + kh * 32;
#pragma unroll
            for (int r = 0; r < 4; r++)
#pragma unroll
                for (int i = 0; i < 8; i++)
                    wfc[r][i] = *(const float4*)(wp + (size_t)r * HDIM + i * 4);
            for (int i = tid; i < FCR; i += NTHR) sm.fcb_s[i] = fcb[g * FCR + i];
        }
    }
    c0r = 0.f; c1r = 0.f;
    __syncthreads();

    // gens: h0d in = (t==0?64:129+t), out = 130+t; h1d in = (t==0?129:193+t),
    //       out = 194+t
    for (int t = 0; t < TLEN; ++t) {
        const int g0i = (t == 0) ? 64 : 129 + t;
        const int g0o = 130 + t;
        const int g1i = (t == 0) ? 129 : 193 + t;
        const int g1o = 194 + t;
        // ---- phase 1: argmax + cell0 (hin slice read direct) ----
        if (t == 0) {
            if (tid < BSZ) sm.tok[tid] = 1;
        } else {
            const float* cvp = cb + (size_t)(fresh ? (t - 1) : ((t - 1) & 1)) * HGEN;
            const float* cip = cvp + 8192;
            if (fresh) {
#pragma unroll
                for (int i = 0; i < 4; i++) {
                    int f = i * 2048 + tid * 4;
                    *(float4*)(sm.hst + f) = *(const float4*)(cvp + f);
                    *(float4*)(sm.hst + 8192 + f) = *(const float4*)(cip + f);
                }
            } else {
#pragma unroll
                for (int i = 0; i < 8; i++) {
                    int f = i * 1024 + tid * 2;
                    *(float2*)(sm.hst + f) = aload2(cvp + f);
                    *(float2*)(sm.hst + 8192 + f) = aload2(cip + f);
                }
            }
            __syncthreads();
            if (tid < 256) {
                int bq = tid >> 3, q = tid & 7;
                float bv = -FLT_MAX; int bi = 0x7fffffff;
                for (int gg = q; gg < FCWGS; gg += 8) {
                    float v = sm.hst[bq * 256 + gg];
                    int ix = ((const int*)sm.hst)[8192 + bq * 256 + gg];
                    if (v > bv || (v == bv && ix < bi)) { bv = v; bi = ix; }
                }
#pragma unroll
                for (int m = 1; m < 8; m <<= 1) {
                    float ov = __shfl_xor(bv, m); int oi = __shfl_xor(bi, m);
                    if (ov > bv || (ov == bv && oi < bi)) { bv = ov; bi = oi; }
                }
                if (q == 0) sm.tok[bq] = bi;
            }
        }
        __syncthreads();
        {
            const float* x0 = dec_emb + (size_t)sm.tok[b] * EDIM;
            float xv0[16], hv0[32];
#pragma unroll
            for (int i = 0; i < 4; i++) {
                float4 v = *(const float4*)(x0 + kq16 * 16 + i * 4);
                xv0[i*4] = v.x; xv0[i*4+1] = v.y; xv0[i*4+2] = v.z; xv0[i*4+3] = v.w;
            }
            read_gslice(genp(hb, g0i, fresh), b, kq16, hv0, fresh);
            cell_compute<EDIM>(sm, sm.w0, sm.bsum0, xv0, hv0,
                               genp(hb, g0i, fresh), genp(hb, g0o, fresh),
                               c0r, false, 0, j0, sm.zsh0, fresh);
        }
        gridbar(flags, sense, epoch);
        // ---- phase 2: cell1 (x = h0new, hin = h1old; both direct) ----
        {
            float xv1[32], hv1[32];
            read_gslice(genp(hb, g0o, fresh), b, kq16, xv1, fresh);
            read_gslice(genp(hb, g1i, fresh), b, kq16, hv1, fresh);
            cell_compute<HDIM>(sm, sm.w1, sm.bsum1, xv1, hv1,
                               genp(hb, g1i, fresh), genp(hb, g1o, fresh),
                               c1r, false, 0, j0, sm.zsh1, fresh);
        }
        gridbar(flags, sense, epoch);
        // ---- phase 3: fc (stages h1new into LDS: 16x intra-WG reuse) ----
        if (g < FCWGS) {
            float* cvt = cb + (size_t)(fresh ? t : (t & 1)) * HGEN;
            fc_run(sm, wfc, genp(hb, g1o, fresh), out, t, g,
                   cvt, (int*)(cvt + 8192), fresh);
        }
        if (t < TLEN - 1)
            gridbar(flags, sense, epoch);
    }
}

// ------------------------------------------------------------------- init ---
__global__ void initk(unsigned* flags)
{
    int i = blockIdx.x * 256 + threadIdx.x;
    if (i < NWG * FSTR + 16) flags[i] = 0u;
}

// ----------------------------------------------------------------- driver ---
extern "C" void kernel_launch(void* const* d_in, const int* in_sizes, int n_in,
                              void* d_out, int out_size, void* d_ws, size_t ws_size,
                              hipStream_t stream)
{
    const int*   inputs  = (const int*)d_in[0];
    const int*   lens    = (const int*)d_in[3];
    const float* enc_emb = (const float*)d_in[4];
    const float* dec_emb = (const float*)d_in[5];
    const float* W[16];
    for (int i = 0; i < 16; i++) W[i] = (const float*)d_in[6 + i];
    const float* fcW = (const float*)d_in[22];
    const float* fcb = (const float*)d_in[23];
    float* out = (float*)d_out;

    float* ws = (float*)d_ws;
    unsigned* flags = (unsigned*)ws;                   // 256*16 + sense line
    float* hb = ws + 8192;                             // h generations
    size_t needB = (size_t)(8192 + (NHG_FRESH + NCG_FRESH) * HGEN) * 4;
    int fresh = (ws_size >= needB) ? 1 : 0;
    float* cb = hb + (size_t)(fresh ? NHG_FRESH : NHG_FB) * HGEN;

    initk<<<17, 256, 0, stream>>>(flags);
    seq2seq_persist<<<NWG, NTHR, 0, stream>>>(
        inputs, lens, enc_emb, dec_emb,
        W[0], W[1], W[2], W[3], W[4], W[5], W[6], W[7],
        W[8], W[9], W[10], W[11], W[12], W[13], W[14], W[15],
        fcW, fcb, out,
        hb, cb, flags, flags + NWG * FSTR, fresh);
}